// Round 1
// baseline (381.198 us; speedup 1.0000x reference)
//
#include <hip/hip_runtime.h>
#include <math.h>

#define DIM   128
#define NC_   50000
#define NE_   100000
#define T_    800000

__device__ __forceinline__ float sigmoidf_(float x) {
    return 1.f / (1.f + __expf(-x));
}

// ---- K0: W_tt = W_t2v @ W_t ; b_tt = b_t2v @ W_t + b_t
__global__ __launch_bounds__(128)
void k_combine(const float* __restrict__ W_t2v, const float* __restrict__ W_t,
               const float* __restrict__ b_t2v, const float* __restrict__ b_t,
               float* __restrict__ W_tt, float* __restrict__ b_tt) {
    const int i = blockIdx.x, j = threadIdx.x;
    float acc = 0.f;
    if (i < DIM) {
        for (int k = 0; k < DIM; ++k) acc = fmaf(W_t2v[i*DIM+k], W_t[k*DIM+j], acc);
        W_tt[i*DIM+j] = acc;
    } else {
        for (int k = 0; k < DIM; ++k) acc = fmaf(b_t2v[k], W_t[k*DIM+j], acc);
        b_tt[j] = acc + b_t[j];
    }
}

// ---- segment start offsets: start[c] = first t with seg[t] >= c ; start[NC_] = T_
__global__ __launch_bounds__(256)
void k_starts(const int* __restrict__ seg, int* __restrict__ start) {
    int t = blockIdx.x * 256 + threadIdx.x;
    if (t > T_) return;
    if (t < T_) {
        int s  = seg[t];
        int sp = (t > 0) ? seg[t-1] : -1;
        for (int c = sp + 1; c <= s; ++c) start[c] = t;
    } else {
        int sp = seg[T_-1];
        for (int c = sp + 1; c <= NC_; ++c) start[c] = T_;
    }
}

// ---- K1: per-edge u[e] = (H_e[e]@W_e + be) * sigmoid(trig(e)@W_tt + b_tt)
__global__ __launch_bounds__(256)
void k_edge(const float* __restrict__ H_e, const float* __restrict__ ts,
            const float* __restrict__ W_e, const float* __restrict__ be_lin,
            const float* __restrict__ b_e, const float* __restrict__ W_tt,
            const float* __restrict__ b_tt, const float* __restrict__ omega,
            float* __restrict__ u) {
    __shared__ float tile[64][DIM];
    const int tid = threadIdx.x;
    const int e0  = blockIdx.x * 64;
    const int cg  = tid & 31, eg = tid >> 5;
    const int j   = cg * 4;

    // phase A: stage H_e tile
    for (int idx = tid; idx < 64 * 32; idx += 256) {
        int r = idx >> 5, c4 = idx & 31;
        int e = e0 + r;
        float4 v = make_float4(0.f, 0.f, 0.f, 0.f);
        if (e < NE_) v = *(const float4*)&H_e[(size_t)e * DIM + c4 * 4];
        *(float4*)&tile[r][c4 * 4] = v;
    }
    __syncthreads();

    float4 accU[8], accG[8];
    #pragma unroll
    for (int i = 0; i < 8; ++i) {
        accU[i] = make_float4(0.f, 0.f, 0.f, 0.f);
        accG[i] = make_float4(0.f, 0.f, 0.f, 0.f);
    }

    #pragma unroll 4
    for (int k = 0; k < DIM; ++k) {
        float4 we = *(const float4*)&W_e[k * DIM + j];
        #pragma unroll
        for (int i = 0; i < 8; ++i) {
            float a = tile[eg * 8 + i][k];
            accU[i].x = fmaf(a, we.x, accU[i].x);
            accU[i].y = fmaf(a, we.y, accU[i].y);
            accU[i].z = fmaf(a, we.z, accU[i].z);
            accU[i].w = fmaf(a, we.w, accU[i].w);
        }
    }
    __syncthreads();

    // phase B: overwrite tile with trig features [cos(t*w) | sin(t*w)]
    for (int idx = tid; idx < 64 * DIM; idx += 256) {
        int r = idx >> 7, k = idx & 127;
        int e = e0 + r;
        float te = (e < NE_) ? ts[e] : 0.f;
        float x = te * omega[k & 63];
        float s, c;
        __sincosf(x, &s, &c);
        tile[r][k] = (k < 64) ? c : s;
    }
    __syncthreads();

    #pragma unroll 4
    for (int k = 0; k < DIM; ++k) {
        float4 wt = *(const float4*)&W_tt[k * DIM + j];
        #pragma unroll
        for (int i = 0; i < 8; ++i) {
            float a = tile[eg * 8 + i][k];
            accG[i].x = fmaf(a, wt.x, accG[i].x);
            accG[i].y = fmaf(a, wt.y, accG[i].y);
            accG[i].z = fmaf(a, wt.z, accG[i].z);
            accG[i].w = fmaf(a, wt.w, accG[i].w);
        }
    }

    float4 be4;
    be4.x = be_lin[j+0] + b_e[j+0];
    be4.y = be_lin[j+1] + b_e[j+1];
    be4.z = be_lin[j+2] + b_e[j+2];
    be4.w = be_lin[j+3] + b_e[j+3];
    float4 bt4 = *(const float4*)&b_tt[j];

    #pragma unroll
    for (int i = 0; i < 8; ++i) {
        int e = e0 + eg * 8 + i;
        if (e < NE_) {
            float4 r;
            r.x = (accU[i].x + be4.x) * sigmoidf_(accG[i].x + bt4.x);
            r.y = (accU[i].y + be4.y) * sigmoidf_(accG[i].y + bt4.y);
            r.z = (accU[i].z + be4.z) * sigmoidf_(accG[i].z + bt4.z);
            r.w = (accU[i].w + be4.w) * sigmoidf_(accG[i].w + bt4.w);
            *(float4*)&u[(size_t)e * DIM + j] = r;
        }
    }
}

// ---- K2: pc[c] = H_c[c] @ W_c + bc_lin + b_c
__global__ __launch_bounds__(256)
void k_code(const float* __restrict__ H_c, const float* __restrict__ W_c,
            const float* __restrict__ bc_lin, const float* __restrict__ b_c,
            float* __restrict__ pc) {
    __shared__ float tile[64][DIM];
    const int tid = threadIdx.x;
    const int c0  = blockIdx.x * 64;
    const int cg  = tid & 31, eg = tid >> 5;
    const int j   = cg * 4;

    for (int idx = tid; idx < 64 * 32; idx += 256) {
        int r = idx >> 5, c4 = idx & 31;
        int c = c0 + r;
        float4 v = make_float4(0.f, 0.f, 0.f, 0.f);
        if (c < NC_) v = *(const float4*)&H_c[(size_t)c * DIM + c4 * 4];
        *(float4*)&tile[r][c4 * 4] = v;
    }
    __syncthreads();

    float4 acc[8];
    #pragma unroll
    for (int i = 0; i < 8; ++i) acc[i] = make_float4(0.f, 0.f, 0.f, 0.f);

    #pragma unroll 4
    for (int k = 0; k < DIM; ++k) {
        float4 wc = *(const float4*)&W_c[k * DIM + j];
        #pragma unroll
        for (int i = 0; i < 8; ++i) {
            float a = tile[eg * 8 + i][k];
            acc[i].x = fmaf(a, wc.x, acc[i].x);
            acc[i].y = fmaf(a, wc.y, acc[i].y);
            acc[i].z = fmaf(a, wc.z, acc[i].z);
            acc[i].w = fmaf(a, wc.w, acc[i].w);
        }
    }

    float4 bc4;
    bc4.x = bc_lin[j+0] + b_c[j+0];
    bc4.y = bc_lin[j+1] + b_c[j+1];
    bc4.z = bc_lin[j+2] + b_c[j+2];
    bc4.w = bc_lin[j+3] + b_c[j+3];

    #pragma unroll
    for (int i = 0; i < 8; ++i) {
        int c = c0 + eg * 8 + i;
        if (c < NC_) {
            float4 r;
            r.x = acc[i].x + bc4.x;
            r.y = acc[i].y + bc4.y;
            r.z = acc[i].z + bc4.z;
            r.w = acc[i].w + bc4.w;
            *(float4*)&pc[(size_t)c * DIM + j] = r;
        }
    }
}

// ---- K3: fused per-code segment softmax + aggregation of H_e rows.
// One wave per code. Reads pc[c] row, overwrites it with v[c] = sum attn*H_e.
__global__ __launch_bounds__(256)
void k_seg(const float* __restrict__ u, float* __restrict__ pcv,
           const float* __restrict__ H_e, const int* __restrict__ edge_ids,
           const int* __restrict__ start) {
    const int lane = threadIdx.x & 63;
    const int c = blockIdx.x * 4 + (threadIdx.x >> 6);
    if (c >= NC_) return;
    const int lo = start[c], hi = start[c + 1];

    float2 pcr = *(const float2*)&pcv[(size_t)c * DIM + lane * 2];
    float M = -INFINITY, S = 0.f;
    float2 acc = make_float2(0.f, 0.f);

    for (int base = lo; base < hi; base += 64) {
        int n = min(64, hi - base);
        float msc = -INFINITY;
        for (int i = 0; i < n; ++i) {
            int e = edge_ids[base + i];
            float2 uv = *(const float2*)&u[(size_t)e * DIM + lane * 2];
            float p = fmaf(uv.x, pcr.x, uv.y * pcr.y);
            #pragma unroll
            for (int off = 32; off; off >>= 1) p += __shfl_xor(p, off);
            if (lane == i) msc = p;
        }
        float cm = msc;
        #pragma unroll
        for (int off = 32; off; off >>= 1) cm = fmaxf(cm, __shfl_xor(cm, off));
        float nM = fmaxf(M, cm);
        float scale = __expf(M - nM);           // M=-inf first pass -> 0
        float pi = (lane < n) ? __expf(msc - nM) : 0.f;
        float ss = pi;
        #pragma unroll
        for (int off = 32; off; off >>= 1) ss += __shfl_xor(ss, off);
        S = S * scale + ss;
        acc.x *= scale; acc.y *= scale;
        M = nM;
        for (int i = 0; i < n; ++i) {
            float p = __shfl(pi, i);
            int e = edge_ids[base + i];
            float2 he = *(const float2*)&H_e[(size_t)e * DIM + lane * 2];
            acc.x = fmaf(p, he.x, acc.x);
            acc.y = fmaf(p, he.y, acc.y);
        }
    }

    float inv = (hi > lo) ? 1.f / fmaxf(S, 1e-30f) : 0.f;
    float2 outv = make_float2(acc.x * inv, acc.y * inv);
    *(float2*)&pcv[(size_t)c * DIM + lane * 2] = outv;
}

// ---- K5: out[c] = has_edge ? 0.5*(v@W_g + b_g) + 0.5*H_c : H_c
__global__ __launch_bounds__(256)
void k_out(const float* __restrict__ v, const float* __restrict__ W_g,
           const float* __restrict__ b_g, const float* __restrict__ H_c,
           const int* __restrict__ start, float* __restrict__ out) {
    __shared__ float tile[64][DIM];
    const int tid = threadIdx.x;
    const int c0  = blockIdx.x * 64;
    const int cg  = tid & 31, eg = tid >> 5;
    const int j   = cg * 4;

    for (int idx = tid; idx < 64 * 32; idx += 256) {
        int r = idx >> 5, c4 = idx & 31;
        int c = c0 + r;
        float4 vv = make_float4(0.f, 0.f, 0.f, 0.f);
        if (c < NC_) vv = *(const float4*)&v[(size_t)c * DIM + c4 * 4];
        *(float4*)&tile[r][c4 * 4] = vv;
    }
    __syncthreads();

    float4 acc[8];
    #pragma unroll
    for (int i = 0; i < 8; ++i) acc[i] = make_float4(0.f, 0.f, 0.f, 0.f);

    #pragma unroll 4
    for (int k = 0; k < DIM; ++k) {
        float4 wg = *(const float4*)&W_g[k * DIM + j];
        #pragma unroll
        for (int i = 0; i < 8; ++i) {
            float a = tile[eg * 8 + i][k];
            acc[i].x = fmaf(a, wg.x, acc[i].x);
            acc[i].y = fmaf(a, wg.y, acc[i].y);
            acc[i].z = fmaf(a, wg.z, acc[i].z);
            acc[i].w = fmaf(a, wg.w, acc[i].w);
        }
    }

    float4 bg4 = *(const float4*)&b_g[j];

    #pragma unroll
    for (int i = 0; i < 8; ++i) {
        int c = c0 + eg * 8 + i;
        if (c < NC_) {
            bool has = start[c + 1] > start[c];
            float4 hc = *(const float4*)&H_c[(size_t)c * DIM + j];
            float4 o;
            if (has) {
                o.x = 0.5f * (acc[i].x + bg4.x) + 0.5f * hc.x;
                o.y = 0.5f * (acc[i].y + bg4.y) + 0.5f * hc.y;
                o.z = 0.5f * (acc[i].z + bg4.z) + 0.5f * hc.z;
                o.w = 0.5f * (acc[i].w + bg4.w) + 0.5f * hc.w;
            } else {
                o = hc;
            }
            *(float4*)&out[(size_t)c * DIM + j] = o;
        }
    }
}

extern "C" void kernel_launch(void* const* d_in, const int* in_sizes, int n_in,
                              void* d_out, int out_size, void* d_ws, size_t ws_size,
                              hipStream_t stream) {
    const float* H_e    = (const float*)d_in[0];
    const float* H_c    = (const float*)d_in[1];
    const float* ts     = (const float*)d_in[2];
    const float* W_e    = (const float*)d_in[3];
    const float* be_lin = (const float*)d_in[4];
    const float* b_e    = (const float*)d_in[5];
    const float* W_c    = (const float*)d_in[6];
    const float* bc_lin = (const float*)d_in[7];
    const float* b_c    = (const float*)d_in[8];
    const float* W_t    = (const float*)d_in[9];
    const float* b_t    = (const float*)d_in[10];
    const float* W_g    = (const float*)d_in[11];
    const float* b_g    = (const float*)d_in[12];
    const float* omega  = (const float*)d_in[13];
    const float* W_t2v  = (const float*)d_in[14];
    const float* b_t2v  = (const float*)d_in[15];
    const int* edge_ids = (const int*)d_in[16];
    const int* seg_ids  = (const int*)d_in[17];
    float* out = (float*)d_out;

    char* w = (char*)d_ws;
    float* u    = (float*)w;  w += (size_t)NE_ * DIM * sizeof(float);
    float* pcv  = (float*)w;  w += (size_t)NC_ * DIM * sizeof(float);
    int* start  = (int*)w;    w += (((size_t)(NC_ + 1) * sizeof(int)) + 255) & ~(size_t)255;
    float* W_tt = (float*)w;  w += (size_t)DIM * DIM * sizeof(float);
    float* b_tt = (float*)w;  w += 256;
    if ((size_t)(w - (char*)d_ws) > ws_size) return;  // insufficient scratch

    k_combine<<<dim3(DIM + 1), dim3(DIM), 0, stream>>>(W_t2v, W_t, b_t2v, b_t, W_tt, b_tt);
    k_starts<<<dim3((T_ + 1 + 255) / 256), dim3(256), 0, stream>>>(seg_ids, start);
    k_edge<<<dim3((NE_ + 63) / 64), dim3(256), 0, stream>>>(H_e, ts, W_e, be_lin, b_e,
                                                            W_tt, b_tt, omega, u);
    k_code<<<dim3((NC_ + 63) / 64), dim3(256), 0, stream>>>(H_c, W_c, bc_lin, b_c, pcv);
    k_seg<<<dim3(NC_ / 4), dim3(256), 0, stream>>>(u, pcv, H_e, edge_ids, start);
    k_out<<<dim3((NC_ + 63) / 64), dim3(256), 0, stream>>>(pcv, W_g, b_g, H_c, start, out);
}

// Round 2
// 309.105 us; speedup vs baseline: 1.2332x; 1.2332x over previous
//
#include <hip/hip_runtime.h>
#include <math.h>

#define DIM   128
#define NC_   50000
#define NE_   100000
#define T_    800000

__device__ __forceinline__ float sigmoidf_(float x) {
    return 1.f / (1.f + __expf(-x));
}

// ---- K0: W_tt = W_t2v @ W_t ; b_tt = b_t2v @ W_t + b_t
__global__ __launch_bounds__(128)
void k_combine(const float* __restrict__ W_t2v, const float* __restrict__ W_t,
               const float* __restrict__ b_t2v, const float* __restrict__ b_t,
               float* __restrict__ W_tt, float* __restrict__ b_tt) {
    const int i = blockIdx.x, j = threadIdx.x;
    float acc = 0.f;
    if (i < DIM) {
        for (int k = 0; k < DIM; ++k) acc = fmaf(W_t2v[i*DIM+k], W_t[k*DIM+j], acc);
        W_tt[i*DIM+j] = acc;
    } else {
        for (int k = 0; k < DIM; ++k) acc = fmaf(b_t2v[k], W_t[k*DIM+j], acc);
        b_tt[j] = acc + b_t[j];
    }
}

// ---- segment start offsets: start[c] = first t with seg[t] >= c ; start[NC_] = T_
__global__ __launch_bounds__(256)
void k_starts(const int* __restrict__ seg, int* __restrict__ start) {
    int t = blockIdx.x * 256 + threadIdx.x;
    if (t > T_) return;
    if (t < T_) {
        int s  = seg[t];
        int sp = (t > 0) ? seg[t-1] : -1;
        for (int c = sp + 1; c <= s; ++c) start[c] = t;
    } else {
        int sp = seg[T_-1];
        for (int c = sp + 1; c <= NC_; ++c) start[c] = T_;
    }
}

// ---- K1: per-edge u[e] = (H_e[e]@W_e + be) * sigmoid(trig(e)@W_tt + b_tt)
__global__ __launch_bounds__(256)
void k_edge(const float* __restrict__ H_e, const float* __restrict__ ts,
            const float* __restrict__ W_e, const float* __restrict__ be_lin,
            const float* __restrict__ b_e, const float* __restrict__ W_tt,
            const float* __restrict__ b_tt, const float* __restrict__ omega,
            float* __restrict__ u) {
    __shared__ float tile[64][DIM];
    const int tid = threadIdx.x;
    const int e0  = blockIdx.x * 64;
    const int cg  = tid & 31, eg = tid >> 5;
    const int j   = cg * 4;

    // phase A: stage H_e tile
    for (int idx = tid; idx < 64 * 32; idx += 256) {
        int r = idx >> 5, c4 = idx & 31;
        int e = e0 + r;
        float4 v = make_float4(0.f, 0.f, 0.f, 0.f);
        if (e < NE_) v = *(const float4*)&H_e[(size_t)e * DIM + c4 * 4];
        *(float4*)&tile[r][c4 * 4] = v;
    }
    __syncthreads();

    float4 accU[8], accG[8];
    #pragma unroll
    for (int i = 0; i < 8; ++i) {
        accU[i] = make_float4(0.f, 0.f, 0.f, 0.f);
        accG[i] = make_float4(0.f, 0.f, 0.f, 0.f);
    }

    #pragma unroll 4
    for (int k = 0; k < DIM; ++k) {
        float4 we = *(const float4*)&W_e[k * DIM + j];
        #pragma unroll
        for (int i = 0; i < 8; ++i) {
            float a = tile[eg * 8 + i][k];
            accU[i].x = fmaf(a, we.x, accU[i].x);
            accU[i].y = fmaf(a, we.y, accU[i].y);
            accU[i].z = fmaf(a, we.z, accU[i].z);
            accU[i].w = fmaf(a, we.w, accU[i].w);
        }
    }
    __syncthreads();

    // phase B: overwrite tile with trig features [cos(t*w) | sin(t*w)]
    for (int idx = tid; idx < 64 * DIM; idx += 256) {
        int r = idx >> 7, k = idx & 127;
        int e = e0 + r;
        float te = (e < NE_) ? ts[e] : 0.f;
        float x = te * omega[k & 63];
        float s, c;
        __sincosf(x, &s, &c);
        tile[r][k] = (k < 64) ? c : s;
    }
    __syncthreads();

    #pragma unroll 4
    for (int k = 0; k < DIM; ++k) {
        float4 wt = *(const float4*)&W_tt[k * DIM + j];
        #pragma unroll
        for (int i = 0; i < 8; ++i) {
            float a = tile[eg * 8 + i][k];
            accG[i].x = fmaf(a, wt.x, accG[i].x);
            accG[i].y = fmaf(a, wt.y, accG[i].y);
            accG[i].z = fmaf(a, wt.z, accG[i].z);
            accG[i].w = fmaf(a, wt.w, accG[i].w);
        }
    }

    float4 be4;
    be4.x = be_lin[j+0] + b_e[j+0];
    be4.y = be_lin[j+1] + b_e[j+1];
    be4.z = be_lin[j+2] + b_e[j+2];
    be4.w = be_lin[j+3] + b_e[j+3];
    float4 bt4 = *(const float4*)&b_tt[j];

    #pragma unroll
    for (int i = 0; i < 8; ++i) {
        int e = e0 + eg * 8 + i;
        if (e < NE_) {
            float4 r;
            r.x = (accU[i].x + be4.x) * sigmoidf_(accG[i].x + bt4.x);
            r.y = (accU[i].y + be4.y) * sigmoidf_(accG[i].y + bt4.y);
            r.z = (accU[i].z + be4.z) * sigmoidf_(accG[i].z + bt4.z);
            r.w = (accU[i].w + be4.w) * sigmoidf_(accG[i].w + bt4.w);
            *(float4*)&u[(size_t)e * DIM + j] = r;
        }
    }
}

// ---- K2: pc[c] = H_c[c] @ W_c + bc_lin + b_c
__global__ __launch_bounds__(256)
void k_code(const float* __restrict__ H_c, const float* __restrict__ W_c,
            const float* __restrict__ bc_lin, const float* __restrict__ b_c,
            float* __restrict__ pc) {
    __shared__ float tile[64][DIM];
    const int tid = threadIdx.x;
    const int c0  = blockIdx.x * 64;
    const int cg  = tid & 31, eg = tid >> 5;
    const int j   = cg * 4;

    for (int idx = tid; idx < 64 * 32; idx += 256) {
        int r = idx >> 5, c4 = idx & 31;
        int c = c0 + r;
        float4 v = make_float4(0.f, 0.f, 0.f, 0.f);
        if (c < NC_) v = *(const float4*)&H_c[(size_t)c * DIM + c4 * 4];
        *(float4*)&tile[r][c4 * 4] = v;
    }
    __syncthreads();

    float4 acc[8];
    #pragma unroll
    for (int i = 0; i < 8; ++i) acc[i] = make_float4(0.f, 0.f, 0.f, 0.f);

    #pragma unroll 4
    for (int k = 0; k < DIM; ++k) {
        float4 wc = *(const float4*)&W_c[k * DIM + j];
        #pragma unroll
        for (int i = 0; i < 8; ++i) {
            float a = tile[eg * 8 + i][k];
            acc[i].x = fmaf(a, wc.x, acc[i].x);
            acc[i].y = fmaf(a, wc.y, acc[i].y);
            acc[i].z = fmaf(a, wc.z, acc[i].z);
            acc[i].w = fmaf(a, wc.w, acc[i].w);
        }
    }

    float4 bc4;
    bc4.x = bc_lin[j+0] + b_c[j+0];
    bc4.y = bc_lin[j+1] + b_c[j+1];
    bc4.z = bc_lin[j+2] + b_c[j+2];
    bc4.w = bc_lin[j+3] + b_c[j+3];

    #pragma unroll
    for (int i = 0; i < 8; ++i) {
        int c = c0 + eg * 8 + i;
        if (c < NC_) {
            float4 r;
            r.x = acc[i].x + bc4.x;
            r.y = acc[i].y + bc4.y;
            r.z = acc[i].z + bc4.z;
            r.w = acc[i].w + bc4.w;
            *(float4*)&pc[(size_t)c * DIM + j] = r;
        }
    }
}

// ---- K3: fused per-code segment softmax + aggregation of H_e rows.
// One wave per code, split into 4 groups of 16 lanes; 4 edges in flight.
// Each lane owns 8 dims: j0 = (lane&15)*8, replicated across the 4 groups.
__global__ __launch_bounds__(256)
void k_seg(const float* __restrict__ u, float* __restrict__ pcv,
           const float* __restrict__ H_e, const int* __restrict__ edge_ids,
           const int* __restrict__ start) {
    const int lane = threadIdx.x & 63;
    const int c = blockIdx.x * 4 + (threadIdx.x >> 6);
    if (c >= NC_) return;
    const int lo = start[c], hi = start[c + 1];
    const int g = lane >> 4;        // group 0..3
    const int q = lane & 15;        // lane within group
    const int j0 = q * 8;           // dim base owned by this lane

    float4 pc0 = *(const float4*)&pcv[(size_t)c * DIM + j0];
    float4 pc1 = *(const float4*)&pcv[(size_t)c * DIM + j0 + 4];

    float M = -INFINITY, S = 0.f;
    float4 a0 = make_float4(0.f, 0.f, 0.f, 0.f);
    float4 a1 = make_float4(0.f, 0.f, 0.f, 0.f);

    for (int base = lo; base < hi; base += 64) {
        const int n = min(64, hi - base);
        const int eid = (base + lane < hi) ? edge_ids[base + lane] : 0;
        const int niter = (n + 3) >> 2;
        float msc = -INFINITY;

        // --- score phase: group g computes slot s = 4*jj + g ---
        for (int jj = 0; jj < niter; ++jj) {
            const int s = 4 * jj + g;
            const int e = __shfl(eid, s);
            float4 u0 = make_float4(0.f, 0.f, 0.f, 0.f);
            float4 u1 = make_float4(0.f, 0.f, 0.f, 0.f);
            if (s < n) {
                const float* up = &u[(size_t)e * DIM + j0];
                u0 = *(const float4*)up;
                u1 = *(const float4*)(up + 4);
            }
            float p = u0.x*pc0.x + u0.y*pc0.y + u0.z*pc0.z + u0.w*pc0.w
                    + u1.x*pc1.x + u1.y*pc1.y + u1.z*pc1.z + u1.w*pc1.w;
            p += __shfl_xor(p, 1);
            p += __shfl_xor(p, 2);
            p += __shfl_xor(p, 4);
            p += __shfl_xor(p, 8);
            if (q == jj && s < n) msc = p;   // lane 16*g+jj holds slot 4*jj+g
        }

        // --- online softmax over the wave (layout is a permutation; max/sum invariant) ---
        float cm = msc;
        #pragma unroll
        for (int off = 32; off; off >>= 1) cm = fmaxf(cm, __shfl_xor(cm, off));
        const float nM = fmaxf(M, cm);
        const float scale = __expf(M - nM);       // first chunk: exp(-inf)=0
        const float pi = __expf(msc - nM);        // unset lanes: exp(-inf)=0
        float ss = pi;
        #pragma unroll
        for (int off = 32; off; off >>= 1) ss += __shfl_xor(ss, off);
        S = S * scale + ss;
        a0.x *= scale; a0.y *= scale; a0.z *= scale; a0.w *= scale;
        a1.x *= scale; a1.y *= scale; a1.z *= scale; a1.w *= scale;
        M = nM;

        // --- aggregation: group g accumulates slot s = 4*jj + g ---
        for (int jj = 0; jj < niter; ++jj) {
            const int s = 4 * jj + g;
            const int e = __shfl(eid, s);
            const float p = __shfl(pi, 16 * g + jj);
            if (s < n) {
                const float* hp = &H_e[(size_t)e * DIM + j0];
                float4 h0 = *(const float4*)hp;
                float4 h1 = *(const float4*)(hp + 4);
                a0.x = fmaf(p, h0.x, a0.x);
                a0.y = fmaf(p, h0.y, a0.y);
                a0.z = fmaf(p, h0.z, a0.z);
                a0.w = fmaf(p, h0.w, a0.w);
                a1.x = fmaf(p, h1.x, a1.x);
                a1.y = fmaf(p, h1.y, a1.y);
                a1.z = fmaf(p, h1.z, a1.z);
                a1.w = fmaf(p, h1.w, a1.w);
            }
        }
    }

    // --- cross-group reduction (groups replicated over dims) ---
    #pragma unroll
    for (int off = 16; off <= 32; off <<= 1) {
        a0.x += __shfl_xor(a0.x, off);
        a0.y += __shfl_xor(a0.y, off);
        a0.z += __shfl_xor(a0.z, off);
        a0.w += __shfl_xor(a0.w, off);
        a1.x += __shfl_xor(a1.x, off);
        a1.y += __shfl_xor(a1.y, off);
        a1.z += __shfl_xor(a1.z, off);
        a1.w += __shfl_xor(a1.w, off);
    }

    if (g == 0) {
        const float inv = (hi > lo) ? 1.f / fmaxf(S, 1e-30f) : 0.f;
        float4 o0, o1;
        o0.x = a0.x * inv; o0.y = a0.y * inv; o0.z = a0.z * inv; o0.w = a0.w * inv;
        o1.x = a1.x * inv; o1.y = a1.y * inv; o1.z = a1.z * inv; o1.w = a1.w * inv;
        *(float4*)&pcv[(size_t)c * DIM + j0]     = o0;
        *(float4*)&pcv[(size_t)c * DIM + j0 + 4] = o1;
    }
}

// ---- K5: out[c] = has_edge ? 0.5*(v@W_g + b_g) + 0.5*H_c : H_c
__global__ __launch_bounds__(256)
void k_out(const float* __restrict__ v, const float* __restrict__ W_g,
           const float* __restrict__ b_g, const float* __restrict__ H_c,
           const int* __restrict__ start, float* __restrict__ out) {
    __shared__ float tile[64][DIM];
    const int tid = threadIdx.x;
    const int c0  = blockIdx.x * 64;
    const int cg  = tid & 31, eg = tid >> 5;
    const int j   = cg * 4;

    for (int idx = tid; idx < 64 * 32; idx += 256) {
        int r = idx >> 5, c4 = idx & 31;
        int c = c0 + r;
        float4 vv = make_float4(0.f, 0.f, 0.f, 0.f);
        if (c < NC_) vv = *(const float4*)&v[(size_t)c * DIM + c4 * 4];
        *(float4*)&tile[r][c4 * 4] = vv;
    }
    __syncthreads();

    float4 acc[8];
    #pragma unroll
    for (int i = 0; i < 8; ++i) acc[i] = make_float4(0.f, 0.f, 0.f, 0.f);

    #pragma unroll 4
    for (int k = 0; k < DIM; ++k) {
        float4 wg = *(const float4*)&W_g[k * DIM + j];
        #pragma unroll
        for (int i = 0; i < 8; ++i) {
            float a = tile[eg * 8 + i][k];
            acc[i].x = fmaf(a, wg.x, acc[i].x);
            acc[i].y = fmaf(a, wg.y, acc[i].y);
            acc[i].z = fmaf(a, wg.z, acc[i].z);
            acc[i].w = fmaf(a, wg.w, acc[i].w);
        }
    }

    float4 bg4 = *(const float4*)&b_g[j];

    #pragma unroll
    for (int i = 0; i < 8; ++i) {
        int c = c0 + eg * 8 + i;
        if (c < NC_) {
            bool has = start[c + 1] > start[c];
            float4 hc = *(const float4*)&H_c[(size_t)c * DIM + j];
            float4 o;
            if (has) {
                o.x = 0.5f * (acc[i].x + bg4.x) + 0.5f * hc.x;
                o.y = 0.5f * (acc[i].y + bg4.y) + 0.5f * hc.y;
                o.z = 0.5f * (acc[i].z + bg4.z) + 0.5f * hc.z;
                o.w = 0.5f * (acc[i].w + bg4.w) + 0.5f * hc.w;
            } else {
                o = hc;
            }
            *(float4*)&out[(size_t)c * DIM + j] = o;
        }
    }
}

extern "C" void kernel_launch(void* const* d_in, const int* in_sizes, int n_in,
                              void* d_out, int out_size, void* d_ws, size_t ws_size,
                              hipStream_t stream) {
    const float* H_e    = (const float*)d_in[0];
    const float* H_c    = (const float*)d_in[1];
    const float* ts     = (const float*)d_in[2];
    const float* W_e    = (const float*)d_in[3];
    const float* be_lin = (const float*)d_in[4];
    const float* b_e    = (const float*)d_in[5];
    const float* W_c    = (const float*)d_in[6];
    const float* bc_lin = (const float*)d_in[7];
    const float* b_c    = (const float*)d_in[8];
    const float* W_t    = (const float*)d_in[9];
    const float* b_t    = (const float*)d_in[10];
    const float* W_g    = (const float*)d_in[11];
    const float* b_g    = (const float*)d_in[12];
    const float* omega  = (const float*)d_in[13];
    const float* W_t2v  = (const float*)d_in[14];
    const float* b_t2v  = (const float*)d_in[15];
    const int* edge_ids = (const int*)d_in[16];
    const int* seg_ids  = (const int*)d_in[17];
    float* out = (float*)d_out;

    char* w = (char*)d_ws;
    float* u    = (float*)w;  w += (size_t)NE_ * DIM * sizeof(float);
    float* pcv  = (float*)w;  w += (size_t)NC_ * DIM * sizeof(float);
    int* start  = (int*)w;    w += (((size_t)(NC_ + 1) * sizeof(int)) + 255) & ~(size_t)255;
    float* W_tt = (float*)w;  w += (size_t)DIM * DIM * sizeof(float);
    float* b_tt = (float*)w;  w += 256;
    if ((size_t)(w - (char*)d_ws) > ws_size) return;  // insufficient scratch

    k_combine<<<dim3(DIM + 1), dim3(DIM), 0, stream>>>(W_t2v, W_t, b_t2v, b_t, W_tt, b_tt);
    k_starts<<<dim3((T_ + 1 + 255) / 256), dim3(256), 0, stream>>>(seg_ids, start);
    k_edge<<<dim3((NE_ + 63) / 64), dim3(256), 0, stream>>>(H_e, ts, W_e, be_lin, b_e,
                                                            W_tt, b_tt, omega, u);
    k_code<<<dim3((NC_ + 63) / 64), dim3(256), 0, stream>>>(H_c, W_c, bc_lin, b_c, pcv);
    k_seg<<<dim3(NC_ / 4), dim3(256), 0, stream>>>(u, pcv, H_e, edge_ids, start);
    k_out<<<dim3((NC_ + 63) / 64), dim3(256), 0, stream>>>(pcv, W_g, b_g, H_c, start, out);
}

// Round 5
// 274.374 us; speedup vs baseline: 1.3893x; 1.1266x over previous
//
#include <hip/hip_runtime.h>
#include <math.h>

#define DIM   128
#define NC_   50000
#define NE_   100000
#define T_    800000

typedef __attribute__((ext_vector_type(8))) short bf16x8;
typedef __attribute__((ext_vector_type(4))) float f32x4;

__device__ __forceinline__ float sigmoidf_(float x) {
    return 1.f / (1.f + __expf(-x));
}
__device__ __forceinline__ unsigned short bf16_rne(float x) {
    unsigned u = __float_as_uint(x);
    return (unsigned short)((u + 0x7FFFu + ((u >> 16) & 1u)) >> 16);
}
__device__ __forceinline__ float bf16f(unsigned short h) {
    return __uint_as_float(((unsigned)h) << 16);
}

// ---- K0: W_tt = W_t2v @ W_t ; b_tt = b_t2v @ W_t + b_t
__global__ __launch_bounds__(128)
void k_combine(const float* __restrict__ W_t2v, const float* __restrict__ W_t,
               const float* __restrict__ b_t2v, const float* __restrict__ b_t,
               float* __restrict__ W_tt, float* __restrict__ b_tt) {
    const int i = blockIdx.x, j = threadIdx.x;
    float acc = 0.f;
    if (i < DIM) {
        for (int k = 0; k < DIM; ++k) acc = fmaf(W_t2v[i*DIM+k], W_t[k*DIM+j], acc);
        W_tt[i*DIM+j] = acc;
    } else {
        for (int k = 0; k < DIM; ++k) acc = fmaf(b_t2v[k], W_t[k*DIM+j], acc);
        b_tt[j] = acc + b_t[j];
    }
}

// ---- pack 128x128 f32 W into split-bf16 B-fragment layout.
// frag elem (nt,kb,lane,e): k = kb*32 + 8*(lane>>4)+e ; n = nt*16 + (lane&15)
// hi plane at [0, 16384), lo plane at [16384, 32768) ushorts.
__global__ __launch_bounds__(64)
void k_pack(const float* __restrict__ s0, const float* __restrict__ s1,
            const float* __restrict__ s2, const float* __restrict__ s3,
            unsigned short* __restrict__ d0, unsigned short* __restrict__ d1,
            unsigned short* __restrict__ d2, unsigned short* __restrict__ d3) {
    const float* srcs[4] = {s0, s1, s2, s3};
    unsigned short* dsts[4] = {d0, d1, d2, d3};
    const float* src = srcs[blockIdx.y];
    unsigned short* dst = dsts[blockIdx.y];
    const int b = blockIdx.x;          // 0..31
    const int nt = b >> 2, kb = b & 3;
    const int lane = threadIdx.x;
    const int n  = nt * 16 + (lane & 15);
    const int k0 = kb * 32 + 8 * (lane >> 4);
    const size_t off = ((size_t)(nt * 4 + kb) * 64 + lane) * 8;
    #pragma unroll
    for (int e = 0; e < 8; ++e) {
        float x = src[(size_t)(k0 + e) * DIM + n];
        unsigned short h = bf16_rne(x);
        dst[off + e]         = h;
        dst[off + e + 16384] = bf16_rne(x - bf16f(h));
    }
}

// ---- segment start offsets: start[c] = first t with seg[t] >= c ; start[NC_] = T_
__global__ __launch_bounds__(256)
void k_starts(const int* __restrict__ seg, int* __restrict__ start) {
    int t = blockIdx.x * 256 + threadIdx.x;
    if (t > T_) return;
    if (t < T_) {
        int s  = seg[t];
        int sp = (t > 0) ? seg[t-1] : -1;
        for (int c = sp + 1; c <= s; ++c) start[c] = t;
    } else {
        int sp = seg[T_-1];
        for (int c = sp + 1; c <= NC_; ++c) start[c] = T_;
    }
}

__device__ __forceinline__ void split8(const float* xs, bf16x8* hi, bf16x8* lo) {
    #pragma unroll
    for (int e = 0; e < 8; ++e) {
        unsigned short h = bf16_rne(xs[e]);
        (*hi)[e] = (short)h;
        (*lo)[e] = (short)bf16_rne(xs[e] - bf16f(h));
    }
}

__device__ __forceinline__ void mfma3(bf16x8 ahi, bf16x8 alo,
                                      const unsigned short* __restrict__ bp,
                                      f32x4* acc) {
    bf16x8 bhi = *(const bf16x8*)bp;
    bf16x8 blo = *(const bf16x8*)(bp + 16384);
    *acc = __builtin_amdgcn_mfma_f32_16x16x32_bf16(ahi, bhi, *acc, 0, 0, 0);
    *acc = __builtin_amdgcn_mfma_f32_16x16x32_bf16(alo, bhi, *acc, 0, 0, 0);
    *acc = __builtin_amdgcn_mfma_f32_16x16x32_bf16(ahi, blo, *acc, 0, 0, 0);
}

// ---- K1: u[e] = (H_e[e]@W_e + be) * sigmoid(trig(e)@W_tt + b_tt)   [MFMA, LDS-free]
__global__ __launch_bounds__(256)
void k_edge(const float* __restrict__ H_e, const float* __restrict__ ts,
            const unsigned short* __restrict__ packWe,
            const unsigned short* __restrict__ packWtt,
            const float* __restrict__ be_lin, const float* __restrict__ b_e,
            const float* __restrict__ b_tt, const float* __restrict__ omega,
            float* __restrict__ u) {
    const int tid  = threadIdx.x;
    const int lane = tid & 63;
    const int q    = lane & 15, g = lane >> 4;
    const int brow = blockIdx.x * 64 + (tid >> 6) * 16;   // wave's 16-row base
    const int arow = brow + q;                            // this lane's A row
    const bool valid = arow < NE_;
    const float* ap = H_e + (size_t)(valid ? arow : 0) * DIM;
    const float te  = valid ? ts[arow] : 0.f;

    f32x4 accU[8], accG[8];
    #pragma unroll
    for (int i = 0; i < 8; ++i) {
        accU[i] = (f32x4){0.f, 0.f, 0.f, 0.f};
        accG[i] = (f32x4){0.f, 0.f, 0.f, 0.f};
    }

    #pragma unroll
    for (int kb = 0; kb < 4; ++kb) {
        const int k0 = kb * 32 + 8 * g;

        // --- A-fragment from H_e row (direct global) ---
        float xs[8];
        if (valid) {
            float4 x0 = *(const float4*)(ap + k0);
            float4 x1 = *(const float4*)(ap + k0 + 4);
            xs[0]=x0.x; xs[1]=x0.y; xs[2]=x0.z; xs[3]=x0.w;
            xs[4]=x1.x; xs[5]=x1.y; xs[6]=x1.z; xs[7]=x1.w;
        } else {
            #pragma unroll
            for (int e = 0; e < 8; ++e) xs[e] = 0.f;
        }
        bf16x8 ahi, alo;
        split8(xs, &ahi, &alo);
        #pragma unroll
        for (int nt = 0; nt < 8; ++nt)
            mfma3(ahi, alo, packWe + ((size_t)(nt * 4 + kb) * 64 + lane) * 8, &accU[nt]);

        // --- A-fragment for trig features [cos | sin] (computed in-register) ---
        float ys[8];
        #pragma unroll
        for (int e = 0; e < 8; ++e) {
            const int k = k0 + e;
            float x = te * omega[k & 63];
            float s, c;
            __sincosf(x, &s, &c);
            ys[e] = (k < 64) ? c : s;
        }
        bf16x8 thi, tlo;
        split8(ys, &thi, &tlo);
        #pragma unroll
        for (int nt = 0; nt < 8; ++nt)
            mfma3(thi, tlo, packWtt + ((size_t)(nt * 4 + kb) * 64 + lane) * 8, &accG[nt]);
    }

    #pragma unroll
    for (int nt = 0; nt < 8; ++nt) {
        const int col = nt * 16 + q;
        const float bu = be_lin[col] + b_e[col];
        const float bg = b_tt[col];
        #pragma unroll
        for (int reg = 0; reg < 4; ++reg) {
            const int e = brow + 4 * g + reg;   // D row = (lane>>4)*4 + reg
            if (e < NE_) {
                float val = (accU[nt][reg] + bu) * sigmoidf_(accG[nt][reg] + bg);
                u[(size_t)e * DIM + col] = val;
            }
        }
    }
}

// ---- K2: pc[c] = H_c[c] @ W_c + bc_lin + b_c   [MFMA, LDS-free]
__global__ __launch_bounds__(256)
void k_code(const float* __restrict__ H_c, const unsigned short* __restrict__ packWc,
            const float* __restrict__ bc_lin, const float* __restrict__ b_c,
            float* __restrict__ pc) {
    const int tid  = threadIdx.x;
    const int lane = tid & 63;
    const int q    = lane & 15, g = lane >> 4;
    const int brow = blockIdx.x * 64 + (tid >> 6) * 16;
    const int arow = brow + q;
    const bool valid = arow < NC_;
    const float* ap = H_c + (size_t)(valid ? arow : 0) * DIM;

    f32x4 acc[8];
    #pragma unroll
    for (int i = 0; i < 8; ++i) acc[i] = (f32x4){0.f, 0.f, 0.f, 0.f};

    #pragma unroll
    for (int kb = 0; kb < 4; ++kb) {
        const int k0 = kb * 32 + 8 * g;
        float xs[8];
        if (valid) {
            float4 x0 = *(const float4*)(ap + k0);
            float4 x1 = *(const float4*)(ap + k0 + 4);
            xs[0]=x0.x; xs[1]=x0.y; xs[2]=x0.z; xs[3]=x0.w;
            xs[4]=x1.x; xs[5]=x1.y; xs[6]=x1.z; xs[7]=x1.w;
        } else {
            #pragma unroll
            for (int e = 0; e < 8; ++e) xs[e] = 0.f;
        }
        bf16x8 ahi, alo;
        split8(xs, &ahi, &alo);
        #pragma unroll
        for (int nt = 0; nt < 8; ++nt)
            mfma3(ahi, alo, packWc + ((size_t)(nt * 4 + kb) * 64 + lane) * 8, &acc[nt]);
    }

    #pragma unroll
    for (int nt = 0; nt < 8; ++nt) {
        const int col = nt * 16 + q;
        const float bc = bc_lin[col] + b_c[col];
        #pragma unroll
        for (int reg = 0; reg < 4; ++reg) {
            const int c = brow + 4 * g + reg;
            if (c < NC_) pc[(size_t)c * DIM + col] = acc[nt][reg] + bc;
        }
    }
}

// ---- K3: fused per-code segment softmax + aggregation of H_e rows.
// One wave per code, 4 groups of 16 lanes, 4 edges in flight.
__global__ __launch_bounds__(256)
void k_seg(const float* __restrict__ u, float* __restrict__ pcv,
           const float* __restrict__ H_e, const int* __restrict__ edge_ids,
           const int* __restrict__ start) {
    const int lane = threadIdx.x & 63;
    const int c = blockIdx.x * 4 + (threadIdx.x >> 6);
    if (c >= NC_) return;
    const int lo = start[c], hi = start[c + 1];
    const int g = lane >> 4;
    const int q = lane & 15;
    const int j0 = q * 8;

    float4 pc0 = *(const float4*)&pcv[(size_t)c * DIM + j0];
    float4 pc1 = *(const float4*)&pcv[(size_t)c * DIM + j0 + 4];

    float M = -INFINITY, S = 0.f;
    float4 a0 = make_float4(0.f, 0.f, 0.f, 0.f);
    float4 a1 = make_float4(0.f, 0.f, 0.f, 0.f);

    for (int base = lo; base < hi; base += 64) {
        const int n = min(64, hi - base);
        const int eid = (base + lane < hi) ? edge_ids[base + lane] : 0;
        const int niter = (n + 3) >> 2;
        float msc = -INFINITY;

        for (int jj = 0; jj < niter; ++jj) {
            const int s = 4 * jj + g;
            const int e = __shfl(eid, s);
            float4 u0 = make_float4(0.f, 0.f, 0.f, 0.f);
            float4 u1 = make_float4(0.f, 0.f, 0.f, 0.f);
            if (s < n) {
                const float* up = &u[(size_t)e * DIM + j0];
                u0 = *(const float4*)up;
                u1 = *(const float4*)(up + 4);
            }
            float p = u0.x*pc0.x + u0.y*pc0.y + u0.z*pc0.z + u0.w*pc0.w
                    + u1.x*pc1.x + u1.y*pc1.y + u1.z*pc1.z + u1.w*pc1.w;
            p += __shfl_xor(p, 1);
            p += __shfl_xor(p, 2);
            p += __shfl_xor(p, 4);
            p += __shfl_xor(p, 8);
            if (q == jj && s < n) msc = p;
        }

        float cm = msc;
        #pragma unroll
        for (int off = 32; off; off >>= 1) cm = fmaxf(cm, __shfl_xor(cm, off));
        const float nM = fmaxf(M, cm);
        const float scale = __expf(M - nM);
        const float pi = __expf(msc - nM);
        float ss = pi;
        #pragma unroll
        for (int off = 32; off; off >>= 1) ss += __shfl_xor(ss, off);
        S = S * scale + ss;
        a0.x *= scale; a0.y *= scale; a0.z *= scale; a0.w *= scale;
        a1.x *= scale; a1.y *= scale; a1.z *= scale; a1.w *= scale;
        M = nM;

        for (int jj = 0; jj < niter; ++jj) {
            const int s = 4 * jj + g;
            const int e = __shfl(eid, s);
            const float p = __shfl(pi, 16 * g + jj);
            if (s < n) {
                const float* hp = &H_e[(size_t)e * DIM + j0];
                float4 h0 = *(const float4*)hp;
                float4 h1 = *(const float4*)(hp + 4);
                a0.x = fmaf(p, h0.x, a0.x);
                a0.y = fmaf(p, h0.y, a0.y);
                a0.z = fmaf(p, h0.z, a0.z);
                a0.w = fmaf(p, h0.w, a0.w);
                a1.x = fmaf(p, h1.x, a1.x);
                a1.y = fmaf(p, h1.y, a1.y);
                a1.z = fmaf(p, h1.z, a1.z);
                a1.w = fmaf(p, h1.w, a1.w);
            }
        }
    }

    #pragma unroll
    for (int off = 16; off <= 32; off <<= 1) {
        a0.x += __shfl_xor(a0.x, off);
        a0.y += __shfl_xor(a0.y, off);
        a0.z += __shfl_xor(a0.z, off);
        a0.w += __shfl_xor(a0.w, off);
        a1.x += __shfl_xor(a1.x, off);
        a1.y += __shfl_xor(a1.y, off);
        a1.z += __shfl_xor(a1.z, off);
        a1.w += __shfl_xor(a1.w, off);
    }

    if (g == 0) {
        const float inv = (hi > lo) ? 1.f / fmaxf(S, 1e-30f) : 0.f;
        float4 o0, o1;
        o0.x = a0.x * inv; o0.y = a0.y * inv; o0.z = a0.z * inv; o0.w = a0.w * inv;
        o1.x = a1.x * inv; o1.y = a1.y * inv; o1.z = a1.z * inv; o1.w = a1.w * inv;
        *(float4*)&pcv[(size_t)c * DIM + j0]     = o0;
        *(float4*)&pcv[(size_t)c * DIM + j0 + 4] = o1;
    }
}

// ---- K5: out[c] = has_edge ? 0.5*(v@W_g + b_g) + 0.5*H_c : H_c   [MFMA, LDS-free]
__global__ __launch_bounds__(256)
void k_out(const float* __restrict__ v, const unsigned short* __restrict__ packWg,
           const float* __restrict__ b_g, const float* __restrict__ H_c,
           const int* __restrict__ start, float* __restrict__ out) {
    const int tid  = threadIdx.x;
    const int lane = tid & 63;
    const int q    = lane & 15, g = lane >> 4;
    const int brow = blockIdx.x * 64 + (tid >> 6) * 16;
    const int arow = brow + q;
    const bool valid = arow < NC_;
    const float* ap = v + (size_t)(valid ? arow : 0) * DIM;

    f32x4 acc[8];
    #pragma unroll
    for (int i = 0; i < 8; ++i) acc[i] = (f32x4){0.f, 0.f, 0.f, 0.f};

    #pragma unroll
    for (int kb = 0; kb < 4; ++kb) {
        const int k0 = kb * 32 + 8 * g;
        float xs[8];
        if (valid) {
            float4 x0 = *(const float4*)(ap + k0);
            float4 x1 = *(const float4*)(ap + k0 + 4);
            xs[0]=x0.x; xs[1]=x0.y; xs[2]=x0.z; xs[3]=x0.w;
            xs[4]=x1.x; xs[5]=x1.y; xs[6]=x1.z; xs[7]=x1.w;
        } else {
            #pragma unroll
            for (int e = 0; e < 8; ++e) xs[e] = 0.f;
        }
        bf16x8 ahi, alo;
        split8(xs, &ahi, &alo);
        #pragma unroll
        for (int nt = 0; nt < 8; ++nt)
            mfma3(ahi, alo, packWg + ((size_t)(nt * 4 + kb) * 64 + lane) * 8, &acc[nt]);
    }

    #pragma unroll
    for (int reg = 0; reg < 4; ++reg) {
        const int c = brow + 4 * g + reg;
        if (c >= NC_) continue;
        const bool has = start[c + 1] > start[c];
        #pragma unroll
        for (int nt = 0; nt < 8; ++nt) {
            const int col = nt * 16 + q;
            const float hc = H_c[(size_t)c * DIM + col];
            float o = has ? 0.5f * (acc[nt][reg] + b_g[col]) + 0.5f * hc : hc;
            out[(size_t)c * DIM + col] = o;
        }
    }
}

extern "C" void kernel_launch(void* const* d_in, const int* in_sizes, int n_in,
                              void* d_out, int out_size, void* d_ws, size_t ws_size,
                              hipStream_t stream) {
    const float* H_e    = (const float*)d_in[0];
    const float* H_c    = (const float*)d_in[1];
    const float* ts     = (const float*)d_in[2];
    const float* W_e    = (const float*)d_in[3];
    const float* be_lin = (const float*)d_in[4];
    const float* b_e    = (const float*)d_in[5];
    const float* W_c    = (const float*)d_in[6];
    const float* bc_lin = (const float*)d_in[7];
    const float* b_c    = (const float*)d_in[8];
    const float* W_t    = (const float*)d_in[9];
    const float* b_t    = (const float*)d_in[10];
    const float* W_g    = (const float*)d_in[11];
    const float* b_g    = (const float*)d_in[12];
    const float* omega  = (const float*)d_in[13];
    const float* W_t2v  = (const float*)d_in[14];
    const float* b_t2v  = (const float*)d_in[15];
    const int* edge_ids = (const int*)d_in[16];
    const int* seg_ids  = (const int*)d_in[17];
    float* out = (float*)d_out;

    char* w = (char*)d_ws;
    float* u    = (float*)w;  w += (size_t)NE_ * DIM * sizeof(float);
    float* pcv  = (float*)w;  w += (size_t)NC_ * DIM * sizeof(float);
    int* start  = (int*)w;    w += (((size_t)(NC_ + 1) * sizeof(int)) + 255) & ~(size_t)255;
    float* W_tt = (float*)w;  w += (size_t)DIM * DIM * sizeof(float);
    float* b_tt = (float*)w;  w += 1024;   // DIM floats = 512 B (+pad). WAS 256 B: b_tt[64..127]
                                           // aliased packWe -> R3/R4 corruption.
    unsigned short* packWe  = (unsigned short*)w; w += 32768 * sizeof(unsigned short);
    unsigned short* packWtt = (unsigned short*)w; w += 32768 * sizeof(unsigned short);
    unsigned short* packWc  = (unsigned short*)w; w += 32768 * sizeof(unsigned short);
    unsigned short* packWg  = (unsigned short*)w; w += 32768 * sizeof(unsigned short);
    if ((size_t)(w - (char*)d_ws) > ws_size) return;  // insufficient scratch

    k_combine<<<dim3(DIM + 1), dim3(128), 0, stream>>>(W_t2v, W_t, b_t2v, b_t, W_tt, b_tt);
    k_pack<<<dim3(32, 4), dim3(64), 0, stream>>>(W_e, W_tt, W_c, W_g,
                                                 packWe, packWtt, packWc, packWg);
    k_starts<<<dim3((T_ + 1 + 255) / 256), dim3(256), 0, stream>>>(seg_ids, start);
    k_edge<<<dim3((NE_ + 63) / 64), dim3(256), 0, stream>>>(H_e, ts, packWe, packWtt,
                                                            be_lin, b_e, b_tt, omega, u);
    k_code<<<dim3((NC_ + 63) / 64), dim3(256), 0, stream>>>(H_c, packWc, bc_lin, b_c, pcv);
    k_seg<<<dim3((NC_ + 3) / 4), dim3(256), 0, stream>>>(u, pcv, H_e, edge_ids, start);
    k_out<<<dim3((NC_ + 63) / 64), dim3(256), 0, stream>>>(pcv, packWg, b_g, H_c, start, out);
}

// Round 6
// 222.820 us; speedup vs baseline: 1.7108x; 1.2314x over previous
//
#include <hip/hip_runtime.h>
#include <math.h>

#define DIM   128
#define NC_   50000
#define NE_   100000
#define T_    800000

typedef __attribute__((ext_vector_type(8))) short bf16x8;
typedef __attribute__((ext_vector_type(4))) float f32x4;

__device__ __forceinline__ float sigmoidf_(float x) {
    return 1.f / (1.f + __expf(-x));
}
__device__ __forceinline__ unsigned short bf16_rne(float x) {
    unsigned u = __float_as_uint(x);
    return (unsigned short)((u + 0x7FFFu + ((u >> 16) & 1u)) >> 16);
}
__device__ __forceinline__ float bf16f(unsigned short h) {
    return __uint_as_float(((unsigned)h) << 16);
}

// ---- K0: W_tt = W_t2v @ W_t ; b_tt = b_t2v @ W_t + b_t
__global__ __launch_bounds__(128)
void k_combine(const float* __restrict__ W_t2v, const float* __restrict__ W_t,
               const float* __restrict__ b_t2v, const float* __restrict__ b_t,
               float* __restrict__ W_tt, float* __restrict__ b_tt) {
    const int i = blockIdx.x, j = threadIdx.x;
    float acc = 0.f;
    if (i < DIM) {
        for (int k = 0; k < DIM; ++k) acc = fmaf(W_t2v[i*DIM+k], W_t[k*DIM+j], acc);
        W_tt[i*DIM+j] = acc;
    } else {
        for (int k = 0; k < DIM; ++k) acc = fmaf(b_t2v[k], W_t[k*DIM+j], acc);
        b_tt[j] = acc + b_t[j];
    }
}

// ---- pack 128x128 f32 W into split-bf16 B-fragment layout.
// frag elem (nt,kb,lane,e): k = kb*32 + 8*(lane>>4)+e ; n = nt*16 + (lane&15)
// hi plane at [0, 16384), lo plane at [16384, 32768) ushorts.
__global__ __launch_bounds__(64)
void k_pack(const float* __restrict__ s0, const float* __restrict__ s1,
            const float* __restrict__ s2, const float* __restrict__ s3,
            unsigned short* __restrict__ d0, unsigned short* __restrict__ d1,
            unsigned short* __restrict__ d2, unsigned short* __restrict__ d3) {
    const float* srcs[4] = {s0, s1, s2, s3};
    unsigned short* dsts[4] = {d0, d1, d2, d3};
    const float* src = srcs[blockIdx.y];
    unsigned short* dst = dsts[blockIdx.y];
    const int b = blockIdx.x;          // 0..31
    const int nt = b >> 2, kb = b & 3;
    const int lane = threadIdx.x;
    const int n  = nt * 16 + (lane & 15);
    const int k0 = kb * 32 + 8 * (lane >> 4);
    const size_t off = ((size_t)(nt * 4 + kb) * 64 + lane) * 8;
    #pragma unroll
    for (int e = 0; e < 8; ++e) {
        float x = src[(size_t)(k0 + e) * DIM + n];
        unsigned short h = bf16_rne(x);
        dst[off + e]         = h;
        dst[off + e + 16384] = bf16_rne(x - bf16f(h));
    }
}

// ---- segment start offsets: start[c] = first t with seg[t] >= c ; start[NC_] = T_
__global__ __launch_bounds__(256)
void k_starts(const int* __restrict__ seg, int* __restrict__ start) {
    int t = blockIdx.x * 256 + threadIdx.x;
    if (t > T_) return;
    if (t < T_) {
        int s  = seg[t];
        int sp = (t > 0) ? seg[t-1] : -1;
        for (int c = sp + 1; c <= s; ++c) start[c] = t;
    } else {
        int sp = seg[T_-1];
        for (int c = sp + 1; c <= NC_; ++c) start[c] = T_;
    }
}

__device__ __forceinline__ void split8(const float* xs, bf16x8* hi, bf16x8* lo) {
    #pragma unroll
    for (int e = 0; e < 8; ++e) {
        unsigned short h = bf16_rne(xs[e]);
        (*hi)[e] = (short)h;
        (*lo)[e] = (short)bf16_rne(xs[e] - bf16f(h));
    }
}

__device__ __forceinline__ void mfma3(bf16x8 ahi, bf16x8 alo,
                                      const unsigned short* __restrict__ bp,
                                      f32x4* acc) {
    bf16x8 bhi = *(const bf16x8*)bp;
    bf16x8 blo = *(const bf16x8*)(bp + 16384);
    *acc = __builtin_amdgcn_mfma_f32_16x16x32_bf16(ahi, bhi, *acc, 0, 0, 0);
    *acc = __builtin_amdgcn_mfma_f32_16x16x32_bf16(alo, bhi, *acc, 0, 0, 0);
    *acc = __builtin_amdgcn_mfma_f32_16x16x32_bf16(ahi, blo, *acc, 0, 0, 0);
}

// ---- K1: u16[e] = bf16((H_e[e]@W_e + be) * sigmoid(trig(e)@W_tt + b_tt))
//          He16[e] = bf16(H_e[e])   (free: lane already holds its 1/4 row)
__global__ __launch_bounds__(256)
void k_edge(const float* __restrict__ H_e, const float* __restrict__ ts,
            const unsigned short* __restrict__ packWe,
            const unsigned short* __restrict__ packWtt,
            const float* __restrict__ be_lin, const float* __restrict__ b_e,
            const float* __restrict__ b_tt, const float* __restrict__ omega,
            unsigned short* __restrict__ u16, unsigned short* __restrict__ He16) {
    const int tid  = threadIdx.x;
    const int lane = tid & 63;
    const int q    = lane & 15, g = lane >> 4;
    const int brow = blockIdx.x * 64 + (tid >> 6) * 16;   // wave's 16-row base
    const int arow = brow + q;                            // this lane's A row
    const bool valid = arow < NE_;
    const float* ap = H_e + (size_t)(valid ? arow : 0) * DIM;
    const float te  = valid ? ts[arow] : 0.f;

    f32x4 accU[8], accG[8];
    #pragma unroll
    for (int i = 0; i < 8; ++i) {
        accU[i] = (f32x4){0.f, 0.f, 0.f, 0.f};
        accG[i] = (f32x4){0.f, 0.f, 0.f, 0.f};
    }

    #pragma unroll
    for (int kb = 0; kb < 4; ++kb) {
        const int k0 = kb * 32 + 8 * g;

        // --- A-fragment from H_e row (direct global) ---
        float xs[8];
        if (valid) {
            float4 x0 = *(const float4*)(ap + k0);
            float4 x1 = *(const float4*)(ap + k0 + 4);
            xs[0]=x0.x; xs[1]=x0.y; xs[2]=x0.z; xs[3]=x0.w;
            xs[4]=x1.x; xs[5]=x1.y; xs[6]=x1.z; xs[7]=x1.w;
        } else {
            #pragma unroll
            for (int e = 0; e < 8; ++e) xs[e] = 0.f;
        }
        bf16x8 ahi, alo;
        split8(xs, &ahi, &alo);
        if (valid) *(bf16x8*)&He16[(size_t)arow * DIM + k0] = ahi;  // bf16 mirror
        #pragma unroll
        for (int nt = 0; nt < 8; ++nt)
            mfma3(ahi, alo, packWe + ((size_t)(nt * 4 + kb) * 64 + lane) * 8, &accU[nt]);

        // --- A-fragment for trig features [cos | sin] (computed in-register) ---
        float ys[8];
        #pragma unroll
        for (int e = 0; e < 8; ++e) {
            const int k = k0 + e;
            float x = te * omega[k & 63];
            float s, c;
            __sincosf(x, &s, &c);
            ys[e] = (k < 64) ? c : s;
        }
        bf16x8 thi, tlo;
        split8(ys, &thi, &tlo);
        #pragma unroll
        for (int nt = 0; nt < 8; ++nt)
            mfma3(thi, tlo, packWtt + ((size_t)(nt * 4 + kb) * 64 + lane) * 8, &accG[nt]);
    }

    #pragma unroll
    for (int nt = 0; nt < 8; ++nt) {
        const int col = nt * 16 + q;
        const float bu = be_lin[col] + b_e[col];
        const float bg = b_tt[col];
        #pragma unroll
        for (int reg = 0; reg < 4; ++reg) {
            const int e = brow + 4 * g + reg;   // D row = (lane>>4)*4 + reg
            if (e < NE_) {
                float val = (accU[nt][reg] + bu) * sigmoidf_(accG[nt][reg] + bg);
                u16[(size_t)e * DIM + col] = bf16_rne(val);
            }
        }
    }
}

// ---- K2: pc[c] = H_c[c] @ W_c + bc_lin + b_c   [MFMA, LDS-free]
__global__ __launch_bounds__(256)
void k_code(const float* __restrict__ H_c, const unsigned short* __restrict__ packWc,
            const float* __restrict__ bc_lin, const float* __restrict__ b_c,
            float* __restrict__ pc) {
    const int tid  = threadIdx.x;
    const int lane = tid & 63;
    const int q    = lane & 15, g = lane >> 4;
    const int brow = blockIdx.x * 64 + (tid >> 6) * 16;
    const int arow = brow + q;
    const bool valid = arow < NC_;
    const float* ap = H_c + (size_t)(valid ? arow : 0) * DIM;

    f32x4 acc[8];
    #pragma unroll
    for (int i = 0; i < 8; ++i) acc[i] = (f32x4){0.f, 0.f, 0.f, 0.f};

    #pragma unroll
    for (int kb = 0; kb < 4; ++kb) {
        const int k0 = kb * 32 + 8 * g;
        float xs[8];
        if (valid) {
            float4 x0 = *(const float4*)(ap + k0);
            float4 x1 = *(const float4*)(ap + k0 + 4);
            xs[0]=x0.x; xs[1]=x0.y; xs[2]=x0.z; xs[3]=x0.w;
            xs[4]=x1.x; xs[5]=x1.y; xs[6]=x1.z; xs[7]=x1.w;
        } else {
            #pragma unroll
            for (int e = 0; e < 8; ++e) xs[e] = 0.f;
        }
        bf16x8 ahi, alo;
        split8(xs, &ahi, &alo);
        #pragma unroll
        for (int nt = 0; nt < 8; ++nt)
            mfma3(ahi, alo, packWc + ((size_t)(nt * 4 + kb) * 64 + lane) * 8, &acc[nt]);
    }

    #pragma unroll
    for (int nt = 0; nt < 8; ++nt) {
        const int col = nt * 16 + q;
        const float bc = bc_lin[col] + b_c[col];
        #pragma unroll
        for (int reg = 0; reg < 4; ++reg) {
            const int c = brow + 4 * g + reg;
            if (c < NC_) pc[(size_t)c * DIM + col] = acc[nt][reg] + bc;
        }
    }
}

// ---- K3: fused per-code segment softmax + aggregation (bf16 gathers).
// One wave per code, 4 groups of 16 lanes, 4 edges in flight.
__global__ __launch_bounds__(256)
void k_seg(const unsigned short* __restrict__ u16, float* __restrict__ pcv,
           const unsigned short* __restrict__ He16, const int* __restrict__ edge_ids,
           const int* __restrict__ start) {
    const int lane = threadIdx.x & 63;
    const int c = blockIdx.x * 4 + (threadIdx.x >> 6);
    if (c >= NC_) return;
    const int lo = start[c], hi = start[c + 1];
    const int g = lane >> 4;
    const int q = lane & 15;
    const int j0 = q * 8;

    float pcr[8];
    {
        float4 p0 = *(const float4*)&pcv[(size_t)c * DIM + j0];
        float4 p1 = *(const float4*)&pcv[(size_t)c * DIM + j0 + 4];
        pcr[0]=p0.x; pcr[1]=p0.y; pcr[2]=p0.z; pcr[3]=p0.w;
        pcr[4]=p1.x; pcr[5]=p1.y; pcr[6]=p1.z; pcr[7]=p1.w;
    }

    float M = -INFINITY, S = 0.f;
    float acc[8];
    #pragma unroll
    for (int i = 0; i < 8; ++i) acc[i] = 0.f;

    for (int base = lo; base < hi; base += 64) {
        const int n = min(64, hi - base);
        const int eid = (base + lane < hi) ? edge_ids[base + lane] : 0;
        const int niter = (n + 3) >> 2;
        float msc = -INFINITY;

        for (int jj = 0; jj < niter; ++jj) {
            const int s = 4 * jj + g;
            const int e = __shfl(eid, s);
            float p = 0.f;
            if (s < n) {
                bf16x8 uv = *(const bf16x8*)&u16[(size_t)e * DIM + j0];
                #pragma unroll
                for (int i = 0; i < 8; ++i)
                    p = fmaf(bf16f((unsigned short)uv[i]), pcr[i], p);
            }
            p += __shfl_xor(p, 1);
            p += __shfl_xor(p, 2);
            p += __shfl_xor(p, 4);
            p += __shfl_xor(p, 8);
            if (q == jj && s < n) msc = p;
        }

        float cm = msc;
        #pragma unroll
        for (int off = 32; off; off >>= 1) cm = fmaxf(cm, __shfl_xor(cm, off));
        const float nM = fmaxf(M, cm);
        const float scale = __expf(M - nM);
        const float pi = __expf(msc - nM);
        float ss = pi;
        #pragma unroll
        for (int off = 32; off; off >>= 1) ss += __shfl_xor(ss, off);
        S = S * scale + ss;
        #pragma unroll
        for (int i = 0; i < 8; ++i) acc[i] *= scale;
        M = nM;

        for (int jj = 0; jj < niter; ++jj) {
            const int s = 4 * jj + g;
            const int e = __shfl(eid, s);
            const float p = __shfl(pi, 16 * g + jj);
            if (s < n) {
                bf16x8 hv = *(const bf16x8*)&He16[(size_t)e * DIM + j0];
                #pragma unroll
                for (int i = 0; i < 8; ++i)
                    acc[i] = fmaf(p, bf16f((unsigned short)hv[i]), acc[i]);
            }
        }
    }

    #pragma unroll
    for (int off = 16; off <= 32; off <<= 1) {
        #pragma unroll
        for (int i = 0; i < 8; ++i) acc[i] += __shfl_xor(acc[i], off);
    }

    if (g == 0) {
        const float inv = (hi > lo) ? 1.f / fmaxf(S, 1e-30f) : 0.f;
        float4 o0, o1;
        o0.x = acc[0] * inv; o0.y = acc[1] * inv; o0.z = acc[2] * inv; o0.w = acc[3] * inv;
        o1.x = acc[4] * inv; o1.y = acc[5] * inv; o1.z = acc[6] * inv; o1.w = acc[7] * inv;
        *(float4*)&pcv[(size_t)c * DIM + j0]     = o0;
        *(float4*)&pcv[(size_t)c * DIM + j0 + 4] = o1;
    }
}

// ---- K5: out[c] = has_edge ? 0.5*(v@W_g + b_g) + 0.5*H_c : H_c   [MFMA, LDS-free]
__global__ __launch_bounds__(256)
void k_out(const float* __restrict__ v, const unsigned short* __restrict__ packWg,
           const float* __restrict__ b_g, const float* __restrict__ H_c,
           const int* __restrict__ start, float* __restrict__ out) {
    const int tid  = threadIdx.x;
    const int lane = tid & 63;
    const int q    = lane & 15, g = lane >> 4;
    const int brow = blockIdx.x * 64 + (tid >> 6) * 16;
    const int arow = brow + q;
    const bool valid = arow < NC_;
    const float* ap = v + (size_t)(valid ? arow : 0) * DIM;

    f32x4 acc[8];
    #pragma unroll
    for (int i = 0; i < 8; ++i) acc[i] = (f32x4){0.f, 0.f, 0.f, 0.f};

    #pragma unroll
    for (int kb = 0; kb < 4; ++kb) {
        const int k0 = kb * 32 + 8 * g;
        float xs[8];
        if (valid) {
            float4 x0 = *(const float4*)(ap + k0);
            float4 x1 = *(const float4*)(ap + k0 + 4);
            xs[0]=x0.x; xs[1]=x0.y; xs[2]=x0.z; xs[3]=x0.w;
            xs[4]=x1.x; xs[5]=x1.y; xs[6]=x1.z; xs[7]=x1.w;
        } else {
            #pragma unroll
            for (int e = 0; e < 8; ++e) xs[e] = 0.f;
        }
        bf16x8 ahi, alo;
        split8(xs, &ahi, &alo);
        #pragma unroll
        for (int nt = 0; nt < 8; ++nt)
            mfma3(ahi, alo, packWg + ((size_t)(nt * 4 + kb) * 64 + lane) * 8, &acc[nt]);
    }

    #pragma unroll
    for (int reg = 0; reg < 4; ++reg) {
        const int c = brow + 4 * g + reg;
        if (c >= NC_) continue;
        const bool has = start[c + 1] > start[c];
        #pragma unroll
        for (int nt = 0; nt < 8; ++nt) {
            const int col = nt * 16 + q;
            const float hc = H_c[(size_t)c * DIM + col];
            float o = has ? 0.5f * (acc[nt][reg] + b_g[col]) + 0.5f * hc : hc;
            out[(size_t)c * DIM + col] = o;
        }
    }
}

extern "C" void kernel_launch(void* const* d_in, const int* in_sizes, int n_in,
                              void* d_out, int out_size, void* d_ws, size_t ws_size,
                              hipStream_t stream) {
    const float* H_e    = (const float*)d_in[0];
    const float* H_c    = (const float*)d_in[1];
    const float* ts     = (const float*)d_in[2];
    const float* W_e    = (const float*)d_in[3];
    const float* be_lin = (const float*)d_in[4];
    const float* b_e    = (const float*)d_in[5];
    const float* W_c    = (const float*)d_in[6];
    const float* bc_lin = (const float*)d_in[7];
    const float* b_c    = (const float*)d_in[8];
    const float* W_t    = (const float*)d_in[9];
    const float* b_t    = (const float*)d_in[10];
    const float* W_g    = (const float*)d_in[11];
    const float* b_g    = (const float*)d_in[12];
    const float* omega  = (const float*)d_in[13];
    const float* W_t2v  = (const float*)d_in[14];
    const float* b_t2v  = (const float*)d_in[15];
    const int* edge_ids = (const int*)d_in[16];
    const int* seg_ids  = (const int*)d_in[17];
    float* out = (float*)d_out;

    char* w = (char*)d_ws;
    unsigned short* u16  = (unsigned short*)w; w += (size_t)NE_ * DIM * sizeof(unsigned short);
    unsigned short* He16 = (unsigned short*)w; w += (size_t)NE_ * DIM * sizeof(unsigned short);
    float* pcv  = (float*)w;  w += (size_t)NC_ * DIM * sizeof(float);
    int* start  = (int*)w;    w += (((size_t)(NC_ + 1) * sizeof(int)) + 255) & ~(size_t)255;
    float* W_tt = (float*)w;  w += (size_t)DIM * DIM * sizeof(float);
    float* b_tt = (float*)w;  w += 1024;   // DIM floats = 512 B + pad (R5 fix)
    unsigned short* packWe  = (unsigned short*)w; w += 32768 * sizeof(unsigned short);
    unsigned short* packWtt = (unsigned short*)w; w += 32768 * sizeof(unsigned short);
    unsigned short* packWc  = (unsigned short*)w; w += 32768 * sizeof(unsigned short);
    unsigned short* packWg  = (unsigned short*)w; w += 32768 * sizeof(unsigned short);
    if ((size_t)(w - (char*)d_ws) > ws_size) return;  // insufficient scratch

    k_combine<<<dim3(DIM + 1), dim3(128), 0, stream>>>(W_t2v, W_t, b_t2v, b_t, W_tt, b_tt);
    k_pack<<<dim3(32, 4), dim3(64), 0, stream>>>(W_e, W_tt, W_c, W_g,
                                                 packWe, packWtt, packWc, packWg);
    k_starts<<<dim3((T_ + 1 + 255) / 256), dim3(256), 0, stream>>>(seg_ids, start);
    k_edge<<<dim3((NE_ + 63) / 64), dim3(256), 0, stream>>>(H_e, ts, packWe, packWtt,
                                                            be_lin, b_e, b_tt, omega,
                                                            u16, He16);
    k_code<<<dim3((NC_ + 63) / 64), dim3(256), 0, stream>>>(H_c, packWc, bc_lin, b_c, pcv);
    k_seg<<<dim3((NC_ + 3) / 4), dim3(256), 0, stream>>>(u16, pcv, He16, edge_ids, start);
    k_out<<<dim3((NC_ + 63) / 64), dim3(256), 0, stream>>>(pcv, packWg, b_g, H_c, start, out);
}

// Round 7
// 148.546 us; speedup vs baseline: 2.5662x; 1.5000x over previous
//
#include <hip/hip_runtime.h>
#include <math.h>

#define DIM   128
#define NC_   50000
#define NE_   100000
#define T_    800000

typedef __attribute__((ext_vector_type(8))) _Float16 f16x8;
typedef __attribute__((ext_vector_type(4))) float f32x4;

__device__ __forceinline__ float sigmoidf_(float x) {
    return 1.f / (1.f + __expf(-x));
}
__device__ __forceinline__ unsigned short bf16_rne(float x) {
    unsigned u = __float_as_uint(x);
    return (unsigned short)((u + 0x7FFFu + ((u >> 16) & 1u)) >> 16);
}
__device__ __forceinline__ float bf16f(unsigned short h) {
    return __uint_as_float(((unsigned)h) << 16);
}

// ---- K0: W_tt = W_t2v @ W_t ; b_tt = b_t2v @ W_t + b_t
__global__ __launch_bounds__(128)
void k_combine(const float* __restrict__ W_t2v, const float* __restrict__ W_t,
               const float* __restrict__ b_t2v, const float* __restrict__ b_t,
               float* __restrict__ W_tt, float* __restrict__ b_tt) {
    const int i = blockIdx.x, j = threadIdx.x;
    float acc = 0.f;
    if (i < DIM) {
        for (int k = 0; k < DIM; ++k) acc = fmaf(W_t2v[i*DIM+k], W_t[k*DIM+j], acc);
        W_tt[i*DIM+j] = acc;
    } else {
        for (int k = 0; k < DIM; ++k) acc = fmaf(b_t2v[k], W_t[k*DIM+j], acc);
        b_tt[j] = acc + b_t[j];
    }
}

// ---- pack 128x128 f32 W into f16 B-fragment layout (single plane, 32KB).
// frag elem (nt,kb,lane,e): k = kb*32 + 8*(lane>>4)+e ; n = nt*16 + (lane&15)
__global__ __launch_bounds__(64)
void k_pack(const float* __restrict__ s0, const float* __restrict__ s1,
            const float* __restrict__ s2, const float* __restrict__ s3,
            _Float16* __restrict__ d0, _Float16* __restrict__ d1,
            _Float16* __restrict__ d2, _Float16* __restrict__ d3) {
    const float* srcs[4] = {s0, s1, s2, s3};
    _Float16* dsts[4] = {d0, d1, d2, d3};
    const float* src = srcs[blockIdx.y];
    _Float16* dst = dsts[blockIdx.y];
    const int b = blockIdx.x;          // 0..31
    const int nt = b >> 2, kb = b & 3;
    const int lane = threadIdx.x;
    const int n  = nt * 16 + (lane & 15);
    const int k0 = kb * 32 + 8 * (lane >> 4);
    const size_t off = ((size_t)(nt * 4 + kb) * 64 + lane) * 8;
    #pragma unroll
    for (int e = 0; e < 8; ++e)
        dst[off + e] = (_Float16)src[(size_t)(k0 + e) * DIM + n];
}

// ---- segment start offsets: start[c] = first t with seg[t] >= c ; start[NC_] = T_
__global__ __launch_bounds__(256)
void k_starts(const int* __restrict__ seg, int* __restrict__ start) {
    int t = blockIdx.x * 256 + threadIdx.x;
    if (t > T_) return;
    if (t < T_) {
        int s  = seg[t];
        int sp = (t > 0) ? seg[t-1] : -1;
        for (int c = sp + 1; c <= s; ++c) start[c] = t;
    } else {
        int sp = seg[T_-1];
        for (int c = sp + 1; c <= NC_; ++c) start[c] = T_;
    }
}

// ---- split f32[8] -> f16 hi + f16 residual
__device__ __forceinline__ void split8h(const float* xs, f16x8* hi, f16x8* lo) {
    #pragma unroll
    for (int e = 0; e < 8; ++e) {
        _Float16 h = (_Float16)xs[e];
        (*hi)[e] = h;
        (*lo)[e] = (_Float16)(xs[e] - (float)h);
    }
}

// ---- stage 32KB pack into LDS (all 256 threads)
__device__ __forceinline__ void stage_lds(_Float16* lds, const _Float16* __restrict__ g) {
    const int tid = threadIdx.x;
    #pragma unroll
    for (int i = 0; i < 8; ++i)
        ((uint4*)lds)[tid + i * 256] = ((const uint4*)g)[tid + i * 256];
}

__device__ __forceinline__ void mfma2(f16x8 ahi, f16x8 alo, const _Float16* lds_bp,
                                      f32x4* acc) {
    f16x8 b = *(const f16x8*)lds_bp;
    *acc = __builtin_amdgcn_mfma_f32_16x16x32_f16(ahi, b, *acc, 0, 0, 0);
    *acc = __builtin_amdgcn_mfma_f32_16x16x32_f16(alo, b, *acc, 0, 0, 0);
}

// ---- K1: u16[e] = bf16((H_e[e]@W_e + be) * sigmoid(trig(e)@W_tt + b_tt))
//          He16[e] = bf16(H_e[e])
__global__ __launch_bounds__(256)
void k_edge(const float* __restrict__ H_e, const float* __restrict__ ts,
            const _Float16* __restrict__ packWe, const _Float16* __restrict__ packWtt,
            const float* __restrict__ be_lin, const float* __restrict__ b_e,
            const float* __restrict__ b_tt, const float* __restrict__ omega,
            unsigned short* __restrict__ u16, unsigned short* __restrict__ He16) {
    __shared__ __align__(16) _Float16 ldsW[16384];   // 32KB, reused U->G
    const int tid  = threadIdx.x;
    const int lane = tid & 63;
    const int q    = lane & 15, g = lane >> 4;
    const int brow = blockIdx.x * 64 + (tid >> 6) * 16;
    const int arow = brow + q;
    const bool valid = arow < NE_;
    const float* ap = H_e + (size_t)(valid ? arow : 0) * DIM;
    const float te  = valid ? ts[arow] : 0.f;

    stage_lds(ldsW, packWe);

    f32x4 accU[8], accG[8];
    #pragma unroll
    for (int i = 0; i < 8; ++i) {
        accU[i] = (f32x4){0.f, 0.f, 0.f, 0.f};
        accG[i] = (f32x4){0.f, 0.f, 0.f, 0.f};
    }
    __syncthreads();

    // ---- GEMM U: H_e row @ We
    #pragma unroll
    for (int kb = 0; kb < 4; ++kb) {
        const int k0 = kb * 32 + 8 * g;
        float xs[8];
        if (valid) {
            float4 x0 = *(const float4*)(ap + k0);
            float4 x1 = *(const float4*)(ap + k0 + 4);
            xs[0]=x0.x; xs[1]=x0.y; xs[2]=x0.z; xs[3]=x0.w;
            xs[4]=x1.x; xs[5]=x1.y; xs[6]=x1.z; xs[7]=x1.w;
            // bf16 mirror of H_e (free)
            unsigned short hh[8];
            #pragma unroll
            for (int e = 0; e < 8; ++e) hh[e] = bf16_rne(xs[e]);
            *(uint4*)&He16[(size_t)arow * DIM + k0] = *(const uint4*)hh;
        } else {
            #pragma unroll
            for (int e = 0; e < 8; ++e) xs[e] = 0.f;
        }
        f16x8 ahi, alo;
        split8h(xs, &ahi, &alo);
        #pragma unroll
        for (int nt = 0; nt < 8; ++nt)
            mfma2(ahi, alo, &ldsW[((nt * 4 + kb) * 64 + lane) * 8], &accU[nt]);
    }

    __syncthreads();             // all U reads done before overwrite
    stage_lds(ldsW, packWtt);
    __syncthreads();

    // ---- GEMM G: trig(e) @ Wtt
    #pragma unroll
    for (int kb = 0; kb < 4; ++kb) {
        const int k0 = kb * 32 + 8 * g;
        float ys[8];
        #pragma unroll
        for (int e = 0; e < 8; ++e) {
            const int k = k0 + e;
            float x = te * omega[k & 63];
            float s, c;
            __sincosf(x, &s, &c);
            ys[e] = (k < 64) ? c : s;
        }
        f16x8 thi, tlo;
        split8h(ys, &thi, &tlo);
        #pragma unroll
        for (int nt = 0; nt < 8; ++nt)
            mfma2(thi, tlo, &ldsW[((nt * 4 + kb) * 64 + lane) * 8], &accG[nt]);
    }

    #pragma unroll
    for (int nt = 0; nt < 8; ++nt) {
        const int col = nt * 16 + q;
        const float bu = be_lin[col] + b_e[col];
        const float bg = b_tt[col];
        #pragma unroll
        for (int reg = 0; reg < 4; ++reg) {
            const int e = brow + 4 * g + reg;   // D row = (lane>>4)*4 + reg
            if (e < NE_) {
                float val = (accU[nt][reg] + bu) * sigmoidf_(accG[nt][reg] + bg);
                u16[(size_t)e * DIM + col] = bf16_rne(val);
            }
        }
    }
}

// ---- K2: pc[c] = H_c[c] @ W_c + bc_lin + b_c
__global__ __launch_bounds__(256)
void k_code(const float* __restrict__ H_c, const _Float16* __restrict__ packWc,
            const float* __restrict__ bc_lin, const float* __restrict__ b_c,
            float* __restrict__ pc) {
    __shared__ __align__(16) _Float16 ldsW[16384];
    const int tid  = threadIdx.x;
    const int lane = tid & 63;
    const int q    = lane & 15, g = lane >> 4;
    const int brow = blockIdx.x * 64 + (tid >> 6) * 16;
    const int arow = brow + q;
    const bool valid = arow < NC_;
    const float* ap = H_c + (size_t)(valid ? arow : 0) * DIM;

    stage_lds(ldsW, packWc);

    f32x4 acc[8];
    #pragma unroll
    for (int i = 0; i < 8; ++i) acc[i] = (f32x4){0.f, 0.f, 0.f, 0.f};
    __syncthreads();

    #pragma unroll
    for (int kb = 0; kb < 4; ++kb) {
        const int k0 = kb * 32 + 8 * g;
        float xs[8];
        if (valid) {
            float4 x0 = *(const float4*)(ap + k0);
            float4 x1 = *(const float4*)(ap + k0 + 4);
            xs[0]=x0.x; xs[1]=x0.y; xs[2]=x0.z; xs[3]=x0.w;
            xs[4]=x1.x; xs[5]=x1.y; xs[6]=x1.z; xs[7]=x1.w;
        } else {
            #pragma unroll
            for (int e = 0; e < 8; ++e) xs[e] = 0.f;
        }
        f16x8 ahi, alo;
        split8h(xs, &ahi, &alo);
        #pragma unroll
        for (int nt = 0; nt < 8; ++nt)
            mfma2(ahi, alo, &ldsW[((nt * 4 + kb) * 64 + lane) * 8], &acc[nt]);
    }

    #pragma unroll
    for (int nt = 0; nt < 8; ++nt) {
        const int col = nt * 16 + q;
        const float bc = bc_lin[col] + b_c[col];
        #pragma unroll
        for (int reg = 0; reg < 4; ++reg) {
            const int c = brow + 4 * g + reg;
            if (c < NC_) pc[(size_t)c * DIM + col] = acc[nt][reg] + bc;
        }
    }
}

// ---- K3: fused per-code segment softmax + aggregation (bf16 gathers).
__global__ __launch_bounds__(256)
void k_seg(const unsigned short* __restrict__ u16, float* __restrict__ pcv,
           const unsigned short* __restrict__ He16, const int* __restrict__ edge_ids,
           const int* __restrict__ start) {
    typedef __attribute__((ext_vector_type(8))) short bf16x8v;
    const int lane = threadIdx.x & 63;
    const int c = blockIdx.x * 4 + (threadIdx.x >> 6);
    if (c >= NC_) return;
    const int lo = start[c], hi = start[c + 1];
    const int g = lane >> 4;
    const int q = lane & 15;
    const int j0 = q * 8;

    float pcr[8];
    {
        float4 p0 = *(const float4*)&pcv[(size_t)c * DIM + j0];
        float4 p1 = *(const float4*)&pcv[(size_t)c * DIM + j0 + 4];
        pcr[0]=p0.x; pcr[1]=p0.y; pcr[2]=p0.z; pcr[3]=p0.w;
        pcr[4]=p1.x; pcr[5]=p1.y; pcr[6]=p1.z; pcr[7]=p1.w;
    }

    float M = -INFINITY, S = 0.f;
    float acc[8];
    #pragma unroll
    for (int i = 0; i < 8; ++i) acc[i] = 0.f;

    for (int base = lo; base < hi; base += 64) {
        const int n = min(64, hi - base);
        const int eid = (base + lane < hi) ? edge_ids[base + lane] : 0;
        const int niter = (n + 3) >> 2;
        float msc = -INFINITY;

        for (int jj = 0; jj < niter; ++jj) {
            const int s = 4 * jj + g;
            const int e = __shfl(eid, s);
            float p = 0.f;
            if (s < n) {
                bf16x8v uv = *(const bf16x8v*)&u16[(size_t)e * DIM + j0];
                #pragma unroll
                for (int i = 0; i < 8; ++i)
                    p = fmaf(bf16f((unsigned short)uv[i]), pcr[i], p);
            }
            p += __shfl_xor(p, 1);
            p += __shfl_xor(p, 2);
            p += __shfl_xor(p, 4);
            p += __shfl_xor(p, 8);
            if (q == jj && s < n) msc = p;
        }

        float cm = msc;
        #pragma unroll
        for (int off = 32; off; off >>= 1) cm = fmaxf(cm, __shfl_xor(cm, off));
        const float nM = fmaxf(M, cm);
        const float scale = __expf(M - nM);
        const float pi = __expf(msc - nM);
        float ss = pi;
        #pragma unroll
        for (int off = 32; off; off >>= 1) ss += __shfl_xor(ss, off);
        S = S * scale + ss;
        #pragma unroll
        for (int i = 0; i < 8; ++i) acc[i] *= scale;
        M = nM;

        for (int jj = 0; jj < niter; ++jj) {
            const int s = 4 * jj + g;
            const int e = __shfl(eid, s);
            const float p = __shfl(pi, 16 * g + jj);
            if (s < n) {
                bf16x8v hv = *(const bf16x8v*)&He16[(size_t)e * DIM + j0];
                #pragma unroll
                for (int i = 0; i < 8; ++i)
                    acc[i] = fmaf(p, bf16f((unsigned short)hv[i]), acc[i]);
            }
        }
    }

    #pragma unroll
    for (int off = 16; off <= 32; off <<= 1) {
        #pragma unroll
        for (int i = 0; i < 8; ++i) acc[i] += __shfl_xor(acc[i], off);
    }

    if (g == 0) {
        const float inv = (hi > lo) ? 1.f / fmaxf(S, 1e-30f) : 0.f;
        float4 o0, o1;
        o0.x = acc[0] * inv; o0.y = acc[1] * inv; o0.z = acc[2] * inv; o0.w = acc[3] * inv;
        o1.x = acc[4] * inv; o1.y = acc[5] * inv; o1.z = acc[6] * inv; o1.w = acc[7] * inv;
        *(float4*)&pcv[(size_t)c * DIM + j0]     = o0;
        *(float4*)&pcv[(size_t)c * DIM + j0 + 4] = o1;
    }
}

// ---- K5: out[c] = has_edge ? 0.5*(v@W_g + b_g) + 0.5*H_c : H_c
__global__ __launch_bounds__(256)
void k_out(const float* __restrict__ v, const _Float16* __restrict__ packWg,
           const float* __restrict__ b_g, const float* __restrict__ H_c,
           const int* __restrict__ start, float* __restrict__ out) {
    __shared__ __align__(16) _Float16 ldsW[16384];
    const int tid  = threadIdx.x;
    const int lane = tid & 63;
    const int q    = lane & 15, g = lane >> 4;
    const int brow = blockIdx.x * 64 + (tid >> 6) * 16;
    const int arow = brow + q;
    const bool valid = arow < NC_;
    const float* ap = v + (size_t)(valid ? arow : 0) * DIM;

    stage_lds(ldsW, packWg);

    f32x4 acc[8];
    #pragma unroll
    for (int i = 0; i < 8; ++i) acc[i] = (f32x4){0.f, 0.f, 0.f, 0.f};
    __syncthreads();

    #pragma unroll
    for (int kb = 0; kb < 4; ++kb) {
        const int k0 = kb * 32 + 8 * g;
        float xs[8];
        if (valid) {
            float4 x0 = *(const float4*)(ap + k0);
            float4 x1 = *(const float4*)(ap + k0 + 4);
            xs[0]=x0.x; xs[1]=x0.y; xs[2]=x0.z; xs[3]=x0.w;
            xs[4]=x1.x; xs[5]=x1.y; xs[6]=x1.z; xs[7]=x1.w;
        } else {
            #pragma unroll
            for (int e = 0; e < 8; ++e) xs[e] = 0.f;
        }
        f16x8 ahi, alo;
        split8h(xs, &ahi, &alo);
        #pragma unroll
        for (int nt = 0; nt < 8; ++nt)
            mfma2(ahi, alo, &ldsW[((nt * 4 + kb) * 64 + lane) * 8], &acc[nt]);
    }

    #pragma unroll
    for (int reg = 0; reg < 4; ++reg) {
        const int c = brow + 4 * g + reg;
        if (c >= NC_) continue;
        const bool has = start[c + 1] > start[c];
        #pragma unroll
        for (int nt = 0; nt < 8; ++nt) {
            const int col = nt * 16 + q;
            const float hc = H_c[(size_t)c * DIM + col];
            float o = has ? 0.5f * (acc[nt][reg] + b_g[col]) + 0.5f * hc : hc;
            out[(size_t)c * DIM + col] = o;
        }
    }
}

extern "C" void kernel_launch(void* const* d_in, const int* in_sizes, int n_in,
                              void* d_out, int out_size, void* d_ws, size_t ws_size,
                              hipStream_t stream) {
    const float* H_e    = (const float*)d_in[0];
    const float* H_c    = (const float*)d_in[1];
    const float* ts     = (const float*)d_in[2];
    const float* W_e    = (const float*)d_in[3];
    const float* be_lin = (const float*)d_in[4];
    const float* b_e    = (const float*)d_in[5];
    const float* W_c    = (const float*)d_in[6];
    const float* bc_lin = (const float*)d_in[7];
    const float* b_c    = (const float*)d_in[8];
    const float* W_t    = (const float*)d_in[9];
    const float* b_t    = (const float*)d_in[10];
    const float* W_g    = (const float*)d_in[11];
    const float* b_g    = (const float*)d_in[12];
    const float* omega  = (const float*)d_in[13];
    const float* W_t2v  = (const float*)d_in[14];
    const float* b_t2v  = (const float*)d_in[15];
    const int* edge_ids = (const int*)d_in[16];
    const int* seg_ids  = (const int*)d_in[17];
    float* out = (float*)d_out;

    char* w = (char*)d_ws;
    unsigned short* u16  = (unsigned short*)w; w += (size_t)NE_ * DIM * sizeof(unsigned short);
    unsigned short* He16 = (unsigned short*)w; w += (size_t)NE_ * DIM * sizeof(unsigned short);
    float* pcv  = (float*)w;  w += (size_t)NC_ * DIM * sizeof(float);
    int* start  = (int*)w;    w += (((size_t)(NC_ + 1) * sizeof(int)) + 255) & ~(size_t)255;
    float* W_tt = (float*)w;  w += (size_t)DIM * DIM * sizeof(float);
    float* b_tt = (float*)w;  w += 1024;   // DIM floats = 512 B + pad (R5 fix)
    _Float16* packWe  = (_Float16*)w; w += 16384 * sizeof(_Float16);
    _Float16* packWtt = (_Float16*)w; w += 16384 * sizeof(_Float16);
    _Float16* packWc  = (_Float16*)w; w += 16384 * sizeof(_Float16);
    _Float16* packWg  = (_Float16*)w; w += 16384 * sizeof(_Float16);
    if ((size_t)(w - (char*)d_ws) > ws_size) return;  // insufficient scratch

    k_combine<<<dim3(DIM + 1), dim3(128), 0, stream>>>(W_t2v, W_t, b_t2v, b_t, W_tt, b_tt);
    k_pack<<<dim3(32, 4), dim3(64), 0, stream>>>(W_e, W_tt, W_c, W_g,
                                                 packWe, packWtt, packWc, packWg);
    k_starts<<<dim3((T_ + 1 + 255) / 256), dim3(256), 0, stream>>>(seg_ids, start);
    k_edge<<<dim3((NE_ + 63) / 64), dim3(256), 0, stream>>>(H_e, ts, packWe, packWtt,
                                                            be_lin, b_e, b_tt, omega,
                                                            u16, He16);
    k_code<<<dim3((NC_ + 63) / 64), dim3(256), 0, stream>>>(H_c, packWc, bc_lin, b_c, pcv);
    k_seg<<<dim3((NC_ + 3) / 4), dim3(256), 0, stream>>>(u16, pcv, He16, edge_ids, start);
    k_out<<<dim3((NC_ + 63) / 64), dim3(256), 0, stream>>>(pcv, packWg, b_g, H_c, start, out);
}